// Round 10
// baseline (148.463 us; speedup 1.0000x reference)
//
#include <hip/hip_runtime.h>

#define QMAX 127.0f

typedef int v4i __attribute__((ext_vector_type(4)));

__device__ __forceinline__ void gload_lds16(const void* g, void* l) {
  __builtin_amdgcn_global_load_lds(
      (const __attribute__((address_space(1))) void*)g,
      (__attribute__((address_space(3))) void*)l, 16, 0, 0);
}

// ---------------- merged prep: pack W0/W1/W2 + quantize x (1 launch) --------
__device__ __forceinline__ void pack_body(const int* __restrict__ W,
                                          signed char* __restrict__ W8,
                                          int* __restrict__ bias,
                                          unsigned lblk, int kshift) {
  unsigned t = lblk * 256u + threadIdx.x;
  unsigned row = t >> kshift;
  unsigned j = t & ((1u << kshift) - 1u);
  unsigned K = 4u << kshift;
  size_t srcBase = (size_t)row * (size_t)(K + 1) + (size_t)j * 4;
  int c0 = W[srcBase + 0], c1 = W[srcBase + 1], c2 = W[srcBase + 2], c3 = W[srcBase + 3];
  unsigned packed = (unsigned)(c0 & 0xff) | ((unsigned)(c1 & 0xff) << 8) |
                    ((unsigned)(c2 & 0xff) << 16) | ((unsigned)(c3 & 0xff) << 24);
  reinterpret_cast<unsigned*>(W8)[t] = packed;
  if (j == 0) bias[row] = W[(size_t)row * (K + 1) + K];
}

__global__ void prep_kernel(const float* __restrict__ x,
                            signed char* __restrict__ qa0,
                            const float* __restrict__ pAin,
                            const int* __restrict__ W0, signed char* __restrict__ W0p, int* __restrict__ b0,
                            const int* __restrict__ W1, signed char* __restrict__ W1p, int* __restrict__ b1,
                            const int* __restrict__ W2, signed char* __restrict__ W2p, int* __restrict__ b2) {
  unsigned blk = blockIdx.x;
  if (blk < 4096u) {
    pack_body(W0, W0p, b0, blk, 8);
  } else if (blk < 20480u) {
    pack_body(W1, W1p, b1, blk - 4096u, 10);
  } else if (blk < 24576u) {
    pack_body(W2, W2p, b2, blk - 20480u, 10);
  } else {
    unsigned t = (blk - 24576u) * 256u + threadIdx.x;
    float s = QMAX / pAin[0];
    float4 v = reinterpret_cast<const float4*>(x)[t];
    int q0 = (int)fminf(fmaxf(rintf(v.x * s), -QMAX), QMAX);
    int q1 = (int)fminf(fmaxf(rintf(v.y * s), -QMAX), QMAX);
    int q2 = (int)fminf(fmaxf(rintf(v.z * s), -QMAX), QMAX);
    int q3 = (int)fminf(fmaxf(rintf(v.w * s), -QMAX), QMAX);
    unsigned packed = (unsigned)(q0 & 0xff) | ((unsigned)(q1 & 0xff) << 8) |
                      ((unsigned)(q2 & 0xff) << 16) | ((unsigned)(q3 & 0xff) << 24);
    reinterpret_cast<unsigned*>(qa0)[t] = packed;
  }
}

#define FENCE() asm volatile("" ::: "memory")
#define BARRIER()                      \
  do {                                 \
    FENCE();                           \
    __builtin_amdgcn_s_barrier();      \
    FENCE();                           \
  } while (0)
#define LGK(n) asm volatile("s_waitcnt lgkmcnt(" #n ")" ::: "memory")
#define VMC(n) asm volatile("s_waitcnt vmcnt(" #n ")" ::: "memory")

// =====================================================================
// 256x256-tile int8 GEMM, 4 WAVES (2Mx2N, per-wave 128x128), ONE WAVE
// PER SIMD. Rationale: all 8-wave (2 waves/SIMD) schedules measured
// port+MFMA SUM because barrier-locked SIMD-partners read together then
// MFMA together. A lone wave self-overlaps: issue next cluster's 16
// ds_reads, then 64 independent MFMAs (~1030cyc pipe backpressure) while
// the port drains the reads. Reads/K-tile drop 192->128 KB.
// lgkmcnt is a 4-BIT field (max 15): LGK(15) drains the 16 current-
// cluster reads + 1 lookahead read (in-order DS retire -> ~free).
// Schedule per tile X (buf p): [enter: R0=kc0(X) reads in flight,
// stage(X+1) in flight]  read kc1(Lp)->R1; LGK(15); MFMA64(R0);
// VMC(0); BAR; read kc0(L~p)->R0; LGK(15); MFMA64(R1); BAR; stage(X+2->Lp).
// WAR: kc1(Lp) reads drained by LGK before 2nd BAR. RAW: VMC(0)+BAR.
// =====================================================================

// stage one 32 KB tile (256 rows x 128 B) with 256 threads: 8 sweeps.
#define STG4(gbase, ldsbuf, t)                                                \
  do {                                                                        \
    _Pragma("unroll") for (int s = 0; s < 8; ++s)                             \
      gload_lds16(gbase + (size_t)(s * 32) * K + (size_t)(t) * 128,           \
                  (ldsbuf) + s * 4096 + tid * 16);                            \
  } while (0)

// 8 ds_read_b128: A m-frags (m=0..7) for k-half kk -> dst[0..7]
#define LDA8k(bf, kk, dst)                                                    \
  do {                                                                        \
    _Pragma("unroll") for (int m = 0; m < 8; ++m) {                           \
      int row = wm * 128 + m * 16 + l15;                                      \
      int off = ((kk) * 64 + hi * 16) ^ ((row & 7) << 4);                     \
      dst[m] = *(const v4i*)(ldsA + (bf) * 32768 + row * 128 + off);          \
    }                                                                         \
  } while (0)

// 8 ds_read_b128: B n-frags (n=0..7) for k-half kk -> dst[0..7]
#define LDB8k(bf, kk, dst)                                                    \
  do {                                                                        \
    _Pragma("unroll") for (int n = 0; n < 8; ++n) {                           \
      int row = wn * 128 + n * 16 + l15;                                      \
      int off = ((kk) * 64 + hi * 16) ^ ((row & 7) << 4);                     \
      dst[n] = *(const v4i*)(ldsB + (bf) * 32768 + row * 128 + off);          \
    }                                                                         \
  } while (0)

// 64 independent MFMA: all 8m x 8n for one k-half
#define MFMA64(aset, bset)                                                    \
  do {                                                                        \
    __builtin_amdgcn_s_setprio(1);                                            \
    _Pragma("unroll") for (int m = 0; m < 8; ++m)                             \
    _Pragma("unroll") for (int n = 0; n < 8; ++n)                             \
      acc[m][n] = __builtin_amdgcn_mfma_i32_16x16x64_i8(                      \
          aset[m], bset[n], acc[m][n], 0, 0, 0);                              \
    __builtin_amdgcn_s_setprio(0);                                            \
  } while (0)

__global__ __launch_bounds__(256, 1)
void qgemm4w_kernel(const signed char* __restrict__ A,
                    const signed char* __restrict__ Bw,
                    const int* __restrict__ bias,
                    signed char* __restrict__ O,
                    int N, int K, int nbn,
                    const float* __restrict__ pAin,
                    const float* __restrict__ pAw,
                    const float* __restrict__ pAnext) {
  extern __shared__ signed char lds[];
  signed char* ldsA = lds;           // A: L0 [0,32K), L1 [32K,64K)
  signed char* ldsB = lds + 65536;   // B: L0 [0,32K), L1 [32K,64K)

  const int nwg = gridDim.x, bid = blockIdx.x, per = nwg >> 3;
  const int swz = (bid & 7) * per + (bid >> 3);
  const int brow = swz / nbn, bcol = swz - brow * nbn;
  const int browBase = brow << 8, bcolBase = bcol << 8;

  const int tid = threadIdx.x;
  const int lane = tid & 63, l15 = lane & 15, hi = lane >> 4;
  const int wid = tid >> 6, wm = wid >> 1, wn = wid & 1;

  // staging thread-constants
  const int r0 = tid >> 3;
  const int osrc = ((tid & 7) ^ (r0 & 7)) << 4;
  const signed char* gA = A + (size_t)(browBase + r0) * K + osrc;
  const signed char* gB = Bw + (size_t)(bcolBase + r0) * K + osrc;

  v4i acc[8][8] = {};
  v4i aR0[8], bR0[8], aR1[8], bR1[8];

  const int nk = K >> 7, niter = nk >> 1, nkm = nk - 1;

  // prologue: stage tile0 -> L0; open; read kc0(L0); stage tile1 -> L1
  STG4(gA, ldsA, 0); STG4(gB, ldsB, 0);
  VMC(0);
  BARRIER();
  LDA8k(0, 0, aR0); LDB8k(0, 0, bR0);
  STG4(gA, ldsA + 32768, 1); STG4(gB, ldsB + 32768, 1);

#pragma unroll 1
  for (int i = 0; i < niter; ++i) {
    const int tE = (2 * i + 2) & nkm;   // wraps at end (reads issued, unused)
    const int tN = (2 * i + 3) & nkm;
    // ---- tile 2i (L0) ----
    LDA8k(0, 1, aR1); LDB8k(0, 1, bR1);   // kc1 reads (16 ds)
    LGK(15);                              // drain kc0 (+1), keep kc1 in flight
    MFMA64(aR0, bR0);
    VMC(0);                               // stage(2i+1 -> L1) landed
    BARRIER();
    LDA8k(1, 0, aR0); LDB8k(1, 0, bR0);   // next tile kc0 (16 ds)
    LGK(15);                              // drain kc1 (+1), keep kc0' in flight
    MFMA64(aR1, bR1);
    BARRIER();                            // all waves' L0 reads drained
    STG4(gA, ldsA, tE); STG4(gB, ldsB, tE);          // stage tE -> L0
    // ---- tile 2i+1 (L1) ----
    LDA8k(1, 1, aR1); LDB8k(1, 1, bR1);
    LGK(15);
    MFMA64(aR0, bR0);
    VMC(0);                               // stage(tE -> L0) landed
    BARRIER();
    LDA8k(0, 0, aR0); LDB8k(0, 0, bR0);
    LGK(15);
    MFMA64(aR1, bR1);
    BARRIER();
    STG4(gA, ldsA + 32768, tN); STG4(gB, ldsB + 32768, tN);  // stage tN -> L1
  }

  VMC(0); LGK(0);  // drain orphan prefetches/reads before epilogue

  const float sDeq = (pAw[0] * pAin[0]) / (QMAX * QMAX);
  const float sQ = QMAX / pAnext[0];
#pragma unroll
  for (int nf = 0; nf < 8; ++nf) {
    const int gcol = bcolBase + wn * 128 + nf * 16 + l15;
    const int bv = bias[gcol];
#pragma unroll
    for (int mf = 0; mf < 8; ++mf) {
      const int gr = browBase + wm * 128 + mf * 16 + (hi << 2);
#pragma unroll
      for (int r = 0; r < 4; ++r) {
        float f = (float)(acc[mf][nf][r] + bv) * sDeq;
        f = fmaxf(f, 0.0f);
        float qf = fminf(fmaxf(rintf(f * sQ), -QMAX), QMAX);
        O[(size_t)(gr + r) * N + gcol] = (signed char)(int)qf;
      }
    }
  }
}

// ---------------- 128x128-tile k-split 2-phase int8 GEMM (layer 2) ----------
#define STG128(bf, t)                                                         \
  do {                                                                        \
    _Pragma("unroll") for (int ii = 0; ii < 4; ++ii) {                        \
      int c = ii * 256 + tid;                                                 \
      int r = c >> 3;                                                         \
      int osrc2 = ((c & 7) << 4) ^ ((r & 7) << 4);                            \
      gload_lds16(A + (size_t)(browBase + r) * K + ((t) * 128 + osrc2),       \
                  ldsA + (bf) * 16384 + c * 16);                              \
      gload_lds16(Bw + (size_t)(bcolBase + r) * K + ((t) * 128 + osrc2),      \
                  ldsB + (bf) * 16384 + c * 16);                              \
    }                                                                         \
  } while (0)

#define LDA4_128(bf, kk, dst)                                                 \
  do {                                                                        \
    _Pragma("unroll") for (int m = 0; m < 4; ++m) {                           \
      int row = wr + m * 16 + l15;                                            \
      int off = ((kk) * 64 + hi * 16) ^ ((row & 7) << 4);                     \
      dst[m] = *(const v4i*)(ldsA + (bf) * 16384 + row * 128 + off);          \
    }                                                                         \
  } while (0)

#define LDB4_128(bf, kk)                                                      \
  do {                                                                        \
    _Pragma("unroll") for (int n = 0; n < 4; ++n) {                           \
      int row = wc + n * 16 + l15;                                            \
      int off = ((kk) * 64 + hi * 16) ^ ((row & 7) << 4);                     \
      bK[n] = *(const v4i*)(ldsB + (bf) * 16384 + row * 128 + off);           \
    }                                                                         \
  } while (0)

#define MFMA16(aset)                                                          \
  do {                                                                        \
    __builtin_amdgcn_s_setprio(1);                                            \
    _Pragma("unroll") for (int m = 0; m < 4; ++m)                             \
    _Pragma("unroll") for (int n = 0; n < 4; ++n)                             \
      acc[m][n] = __builtin_amdgcn_mfma_i32_16x16x64_i8(                      \
          aset[m], bK[n], acc[m][n], 0, 0, 0);                                \
    __builtin_amdgcn_s_setprio(0);                                            \
  } while (0)

__global__ __launch_bounds__(256)
void qgemm_kernel(const signed char* __restrict__ A,
                  const signed char* __restrict__ Bw,
                  const int* __restrict__ bias,
                  float* __restrict__ O,
                  int N, int K, int nbn,
                  const float* __restrict__ pAin,
                  const float* __restrict__ pAw) {
  __shared__ signed char slds[65536];
  signed char* ldsA = slds;            // bufs at 0 / 16K
  signed char* ldsB = slds + 32768;    // bufs at 0 / 16K

  const int nwg = gridDim.x, bid = blockIdx.x, per = nwg >> 3;
  const int swz = (bid & 7) * per + (bid >> 3);
  const int brow = swz / nbn, bcol = swz - brow * nbn;
  const int browBase = brow << 7, bcolBase = bcol << 7;

  const int tid = threadIdx.x;
  const int lane = tid & 63, l15 = lane & 15, hi = lane >> 4;
  const int wid = tid >> 6;
  const int wr = (wid >> 1) << 6, wc = (wid & 1) << 6;

  v4i acc[4][4] = {};
  v4i aK0[4], aK1[4], bK[4];

  const int nk = K >> 7, niter = nk >> 1, nkm = nk - 1;

  STG128(0, 0);
  VMC(0);
  BARRIER();
  LDA4_128(0, 0, aK0);

#pragma unroll 1
  for (int i = 0; i < niter; ++i) {
    const int tO = 2 * i + 1;
    const int tE = (2 * i + 2) & nkm;
    // tile 2i (buf0)
    LGK(4);
    BARRIER();
    STG128(1, tO);
    LDB4_128(0, 0); FENCE(); LDA4_128(0, 1, aK1);
    LGK(4);
    MFMA16(aK0);
    VMC(0);
    BARRIER();
    LDB4_128(0, 1); FENCE(); LDA4_128(1, 0, aK0);
    LGK(4);
    MFMA16(aK1);
    // tile 2i+1 (buf1)
    LGK(4);
    BARRIER();
    STG128(0, tE);
    LDB4_128(1, 0); FENCE(); LDA4_128(1, 1, aK1);
    LGK(4);
    MFMA16(aK0);
    VMC(0);
    BARRIER();
    LDB4_128(1, 1); FENCE(); LDA4_128(0, 0, aK0);
    LGK(4);
    MFMA16(aK1);
  }

  VMC(0);

  const float sDeq = (pAw[0] * pAin[0]) / (QMAX * QMAX);
#pragma unroll
  for (int n = 0; n < 4; ++n) {
    int gcol = bcolBase + wc + n * 16 + l15;
    int bv = bias[gcol];
#pragma unroll
    for (int m = 0; m < 4; ++m) {
      int growb = browBase + wr + m * 16 + (hi << 2);
#pragma unroll
      for (int r = 0; r < 4; ++r) {
        O[(size_t)(growb + r) * N + gcol] = (float)(acc[m][n][r] + bv) * sDeq;
      }
    }
  }
}

extern "C" void kernel_launch(void* const* d_in, const int* in_sizes, int n_in,
                              void* d_out, int out_size, void* d_ws, size_t ws_size,
                              hipStream_t stream) {
  const float* x     = (const float*)d_in[0];
  const float* a_in0 = (const float*)d_in[1];
  const float* a_w0  = (const float*)d_in[2];
  const float* a_in2 = (const float*)d_in[3];
  const float* a_w2  = (const float*)d_in[4];
  const float* a_in4 = (const float*)d_in[5];
  const float* a_w4  = (const float*)d_in[6];
  const int*   W0    = (const int*)d_in[7];
  const int*   W1    = (const int*)d_in[8];
  const int*   W2    = (const int*)d_in[9];
  float* out = (float*)d_out;

  constexpr int B = 4096, IN = 1024, H0 = 4096, H1 = 4096, OUTN = 1024;

  char* ws = (char*)d_ws;
  size_t off = 0;
  auto alloc = [&](size_t sz) {
    char* p = ws + off;
    off += (sz + 255) & ~(size_t)255;
    return p;
  };
  signed char* qa0 = (signed char*)alloc((size_t)B * IN);
  signed char* qa1 = (signed char*)alloc((size_t)B * H0);
  signed char* qa2 = (signed char*)alloc((size_t)B * H1);
  signed char* W0p = (signed char*)alloc((size_t)H0 * IN);
  signed char* W1p = (signed char*)alloc((size_t)H1 * H0);
  signed char* W2p = (signed char*)alloc((size_t)OUTN * H1);
  int* b0 = (int*)alloc((size_t)H0 * 4);
  int* b1 = (int*)alloc((size_t)H1 * 4);
  int* b2 = (int*)alloc((size_t)OUTN * 4);

  hipFuncSetAttribute((const void*)qgemm4w_kernel,
                      hipFuncAttributeMaxDynamicSharedMemorySize, 131072);

  // merged prep: pack W0/W1/W2 + quantize x (1 launch, 28672 blocks)
  prep_kernel<<<28672, 256, 0, stream>>>(x, qa0, a_in0,
                                         W0, W0p, b0,
                                         W1, W1p, b1,
                                         W2, W2p, b2);

  // layer 0: [B,IN]x[H0,IN]^T -> qa1 (int8), 4-wave 256^2, grid 16x16=256
  qgemm4w_kernel<<<(B / 256) * (H0 / 256), 256, 131072, stream>>>(
      qa0, W0p, b0, qa1, H0, IN, H0 / 256, a_in0, a_w0, a_in2);

  // layer 1: [B,H0]x[H1,H0]^T -> qa2 (int8), 4-wave 256^2, grid 16x16=256
  qgemm4w_kernel<<<(B / 256) * (H1 / 256), 256, 131072, stream>>>(
      qa1, W1p, b1, qa2, H1, H0, H1 / 256, a_in2, a_w2, a_in4);

  // layer 2: [B,H1]x[OUT,H1]^T -> f32 out, 128^2 k-split, grid 32x8=256
  qgemm_kernel<<<(B / 128) * (OUTN / 128), 256, 0, stream>>>(
      qa2, W2p, b2, out, OUTN, H1, OUTN / 128, a_in4, a_w4);
}

// Round 11
// 132.392 us; speedup vs baseline: 1.1214x; 1.1214x over previous
//
#include <hip/hip_runtime.h>

#define QMAX 127.0f

typedef int v4i __attribute__((ext_vector_type(4)));

__device__ __forceinline__ void gload_lds16(const void* g, void* l) {
  __builtin_amdgcn_global_load_lds(
      (const __attribute__((address_space(1))) void*)g,
      (__attribute__((address_space(3))) void*)l, 16, 0, 0);
}

// ---------------- merged prep: pack W0/W1/W2 + quantize x (1 launch) --------
__device__ __forceinline__ void pack_body(const int* __restrict__ W,
                                          signed char* __restrict__ W8,
                                          int* __restrict__ bias,
                                          unsigned lblk, int kshift) {
  unsigned t = lblk * 256u + threadIdx.x;
  unsigned row = t >> kshift;
  unsigned j = t & ((1u << kshift) - 1u);
  unsigned K = 4u << kshift;
  size_t srcBase = (size_t)row * (size_t)(K + 1) + (size_t)j * 4;
  int c0 = W[srcBase + 0], c1 = W[srcBase + 1], c2 = W[srcBase + 2], c3 = W[srcBase + 3];
  unsigned packed = (unsigned)(c0 & 0xff) | ((unsigned)(c1 & 0xff) << 8) |
                    ((unsigned)(c2 & 0xff) << 16) | ((unsigned)(c3 & 0xff) << 24);
  reinterpret_cast<unsigned*>(W8)[t] = packed;
  if (j == 0) bias[row] = W[(size_t)row * (K + 1) + K];
}

__global__ void prep_kernel(const float* __restrict__ x,
                            signed char* __restrict__ qa0,
                            const float* __restrict__ pAin,
                            const int* __restrict__ W0, signed char* __restrict__ W0p, int* __restrict__ b0,
                            const int* __restrict__ W1, signed char* __restrict__ W1p, int* __restrict__ b1,
                            const int* __restrict__ W2, signed char* __restrict__ W2p, int* __restrict__ b2) {
  unsigned blk = blockIdx.x;
  if (blk < 4096u) {
    pack_body(W0, W0p, b0, blk, 8);
  } else if (blk < 20480u) {
    pack_body(W1, W1p, b1, blk - 4096u, 10);
  } else if (blk < 24576u) {
    pack_body(W2, W2p, b2, blk - 20480u, 10);
  } else {
    unsigned t = (blk - 24576u) * 256u + threadIdx.x;
    float s = QMAX / pAin[0];
    float4 v = reinterpret_cast<const float4*>(x)[t];
    int q0 = (int)fminf(fmaxf(rintf(v.x * s), -QMAX), QMAX);
    int q1 = (int)fminf(fmaxf(rintf(v.y * s), -QMAX), QMAX);
    int q2 = (int)fminf(fmaxf(rintf(v.z * s), -QMAX), QMAX);
    int q3 = (int)fminf(fmaxf(rintf(v.w * s), -QMAX), QMAX);
    unsigned packed = (unsigned)(q0 & 0xff) | ((unsigned)(q1 & 0xff) << 8) |
                      ((unsigned)(q2 & 0xff) << 16) | ((unsigned)(q3 & 0xff) << 24);
    reinterpret_cast<unsigned*>(qa0)[t] = packed;
  }
}

// =====================================================================
// 256x256-tile 8-phase int8 GEMM (round-3 verified schedule, best
// measured gemm1 = 63.2 us). 8 waves (2M x 4N), per-wave out 128x64,
// BK=128 B, LDS 128 KiB dbuf. MFMA clusters split by (M-quadrant,
// k-half); vmcnt(6) at ph4/ph8 only; LGK0 closes at ph1/3/5/7.
// =====================================================================

#define FENCE() asm volatile("" ::: "memory")
#define BARRIER()                      \
  do {                                 \
    FENCE();                           \
    __builtin_amdgcn_s_barrier();      \
    FENCE();                           \
  } while (0)
#define LGK0() asm volatile("s_waitcnt lgkmcnt(0)" ::: "memory")
#define LGK(n) asm volatile("s_waitcnt lgkmcnt(" #n ")" ::: "memory")
#define VMC6() asm volatile("s_waitcnt vmcnt(6)" ::: "memory")
#define VMC0() asm volatile("s_waitcnt vmcnt(0)" ::: "memory")

#define STAGE_A(bf, h, t)                                                     \
  do {                                                                        \
    const signed char* _g = gA + (size_t)((h) * 128) * K + (size_t)(t) * 128; \
    signed char* _l = ldsA + (bf) * 32768 + (h) * 16384 + ldsThr;             \
    gload_lds16(_g, _l);                                                      \
    gload_lds16(_g + (size_t)8 * K, _l + 1024);                               \
  } while (0)

#define STAGE_B(bf, h, t)                                                     \
  do {                                                                        \
    const signed char* _g = gB + (size_t)((h) * 128) * K + (size_t)(t) * 128; \
    signed char* _l = ldsB + (bf) * 32768 + (h) * 16384 + ldsThr;             \
    gload_lds16(_g, _l);                                                      \
    gload_lds16(_g + (size_t)8 * K, _l + 1024);                               \
  } while (0)

// 4 ds_read_b128: A quadrant qm, k-half kk -> dst[0..3]
#define LDAQ(bf, qm, kk, dst)                                                 \
  do {                                                                        \
    _Pragma("unroll") for (int m = 0; m < 4; ++m) {                           \
      int row = wm * 128 + (qm) * 64 + m * 16 + l15;                          \
      int off = ((kk) * 64 + hi * 16) ^ ((row & 7) << 4);                     \
      dst[m] = *(const v4i*)(ldsA + (bf) * 32768 + row * 128 + off);          \
    }                                                                         \
  } while (0)

// 4 ds_read_b128: B all-n, k-half kk -> bR[n][kk]
#define LDBH(bf, kk)                                                          \
  do {                                                                        \
    _Pragma("unroll") for (int n = 0; n < 4; ++n) {                           \
      int row = wn * 64 + n * 16 + l15;                                       \
      int off = ((kk) * 64 + hi * 16) ^ ((row & 7) << 4);                     \
      bR[n][kk] = *(const v4i*)(ldsB + (bf) * 32768 + row * 128 + off);       \
    }                                                                         \
  } while (0)

// 16 MFMA: quadrant qm, k-half kk, A operands in asrc[0..3]
#define MFMAQK(qm, kk, asrc)                                                  \
  do {                                                                        \
    __builtin_amdgcn_s_setprio(1);                                            \
    _Pragma("unroll") for (int m = 0; m < 4; ++m)                             \
    _Pragma("unroll") for (int n = 0; n < 4; ++n)                             \
      acc[(qm) * 4 + m][n] = __builtin_amdgcn_mfma_i32_16x16x64_i8(           \
          asrc[m], bR[n][kk], acc[(qm) * 4 + m][n], 0, 0, 0);                 \
    __builtin_amdgcn_s_setprio(0);                                            \
  } while (0)

__global__ __launch_bounds__(512, 2)
void qgemm256_kernel(const signed char* __restrict__ A,
                     const signed char* __restrict__ Bw,
                     const int* __restrict__ bias,
                     signed char* __restrict__ O,
                     int N, int K, int nbn,
                     const float* __restrict__ pAin,
                     const float* __restrict__ pAw,
                     const float* __restrict__ pAnext) {
  extern __shared__ signed char lds[];
  signed char* ldsA = lds;           // buf0 [0,32K), buf1 [32K,64K)
  signed char* ldsB = lds + 65536;

  const int nwg = gridDim.x, bid = blockIdx.x, per = nwg >> 3;
  const int swz = (bid & 7) * per + (bid >> 3);
  const int brow = swz / nbn, bcol = swz - brow * nbn;
  const int browBase = brow << 8, bcolBase = bcol << 8;

  const int tid = threadIdx.x;
  const int lane = tid & 63, l15 = lane & 15, hi = lane >> 4;
  const int wid = tid >> 6, wm = wid >> 2, wn = wid & 3;

  const int rloc = (wid << 4) + (lane >> 3);
  const int csrc = (lane & 7) ^ ((lane >> 3) & 7);
  const signed char* gA = A + (size_t)(browBase + rloc) * K + csrc * 16;
  const signed char* gB = Bw + (size_t)(bcolBase + rloc) * K + csrc * 16;
  const int ldsThr = (wid << 11) + lane * 16;

  v4i acc[8][4] = {};
  v4i bR[4][2];

  const int nk = K >> 7, niter = nk >> 1, nkm = nk - 1;

  // prologue: t0 {B0,B1,A0,A1}, t1 {B0,B1,A0}; leave 3 half-tiles (6) in flight
  STAGE_B(0, 0, 0); STAGE_B(0, 1, 0); STAGE_A(0, 0, 0); STAGE_A(0, 1, 0);
  STAGE_B(1, 0, 1); STAGE_B(1, 1, 1); STAGE_A(1, 0, 1);
  VMC6();
  BARRIER();

#pragma unroll 1
  for (int i = 0; i < niter; ++i) {
    const int t1 = 2 * i + 1;
    const int tE = (2 * i + 2) & nkm;   // wrapped: always issue (exact vmcnt)
    const int tO = (2 * i + 3) & nkm;
    v4i a00[4], a01[4], a10[4], a11[4];
    // ---- even half (buf0) ----
    LDAQ(0, 0, 0, a00); LDBH(0, 0); LDAQ(0, 0, 1, a01); LDBH(0, 1);
    STAGE_A(1, 1, t1);
    BARRIER();
    MFMAQK(0, 0, a00);
    LGK0();
    BARRIER();
    LDAQ(0, 1, 0, a10);
    STAGE_B(0, 0, tE);
    BARRIER();
    MFMAQK(0, 1, a01);
    BARRIER();
    LDAQ(0, 1, 1, a11);
    STAGE_B(0, 1, tE);
    BARRIER();
    MFMAQK(1, 0, a10);
    LGK0();
    BARRIER();
    STAGE_A(0, 0, tE);
    VMC6();
    BARRIER();
    MFMAQK(1, 1, a11);
    BARRIER();
    // ---- odd half (buf1) ----
    LDAQ(1, 0, 0, a00); LDBH(1, 0); LDAQ(1, 0, 1, a01); LDBH(1, 1);
    STAGE_A(0, 1, tE);
    BARRIER();
    MFMAQK(0, 0, a00);
    LGK0();
    BARRIER();
    LDAQ(1, 1, 0, a10);
    STAGE_B(1, 0, tO);
    BARRIER();
    MFMAQK(0, 1, a01);
    BARRIER();
    LDAQ(1, 1, 1, a11);
    STAGE_B(1, 1, tO);
    BARRIER();
    MFMAQK(1, 0, a10);
    LGK0();
    BARRIER();
    STAGE_A(1, 0, tO);
    VMC6();
    BARRIER();
    MFMAQK(1, 1, a11);
    BARRIER();
  }

  VMC0();  // drain orphan prefetches before epilogue

  const float sDeq = (pAw[0] * pAin[0]) / (QMAX * QMAX);
  const float sQ = QMAX / pAnext[0];
#pragma unroll
  for (int nf = 0; nf < 4; ++nf) {
    const int gcol = bcolBase + wn * 64 + nf * 16 + l15;
    const int bv = bias[gcol];
#pragma unroll
    for (int mf = 0; mf < 8; ++mf) {
      const int gr = browBase + wm * 128 + mf * 16 + (hi << 2);
#pragma unroll
      for (int r = 0; r < 4; ++r) {
        float f = (float)(acc[mf][nf][r] + bv) * sDeq;
        f = fmaxf(f, 0.0f);
        float qf = fminf(fmaxf(rintf(f * sQ), -QMAX), QMAX);
        O[(size_t)(gr + r) * N + gcol] = (signed char)(int)qf;
      }
    }
  }
}

// ---------------- 128x128-tile k-split 2-phase int8 GEMM (layer 2) ----------
#define STG128(bf, t)                                                         \
  do {                                                                        \
    _Pragma("unroll") for (int ii = 0; ii < 4; ++ii) {                        \
      int c = ii * 256 + tid;                                                 \
      int r = c >> 3;                                                         \
      int osrc2 = ((c & 7) << 4) ^ ((r & 7) << 4);                            \
      gload_lds16(A + (size_t)(browBase + r) * K + ((t) * 128 + osrc2),       \
                  ldsA + (bf) * 16384 + c * 16);                              \
      gload_lds16(Bw + (size_t)(bcolBase + r) * K + ((t) * 128 + osrc2),      \
                  ldsB + (bf) * 16384 + c * 16);                              \
    }                                                                         \
  } while (0)

#define LDA4_128(bf, kk, dst)                                                 \
  do {                                                                        \
    _Pragma("unroll") for (int m = 0; m < 4; ++m) {                           \
      int row = wr + m * 16 + l15;                                            \
      int off = ((kk) * 64 + hi * 16) ^ ((row & 7) << 4);                     \
      dst[m] = *(const v4i*)(ldsA + (bf) * 16384 + row * 128 + off);          \
    }                                                                         \
  } while (0)

#define LDB4_128(bf, kk)                                                      \
  do {                                                                        \
    _Pragma("unroll") for (int n = 0; n < 4; ++n) {                           \
      int row = wc + n * 16 + l15;                                            \
      int off = ((kk) * 64 + hi * 16) ^ ((row & 7) << 4);                     \
      bK[n] = *(const v4i*)(ldsB + (bf) * 16384 + row * 128 + off);           \
    }                                                                         \
  } while (0)

#define MFMA16(aset)                                                          \
  do {                                                                        \
    __builtin_amdgcn_s_setprio(1);                                            \
    _Pragma("unroll") for (int m = 0; m < 4; ++m)                             \
    _Pragma("unroll") for (int n = 0; n < 4; ++n)                             \
      acc[m][n] = __builtin_amdgcn_mfma_i32_16x16x64_i8(                      \
          aset[m], bK[n], acc[m][n], 0, 0, 0);                                \
    __builtin_amdgcn_s_setprio(0);                                            \
  } while (0)

__global__ __launch_bounds__(256)
void qgemm_kernel(const signed char* __restrict__ A,
                  const signed char* __restrict__ Bw,
                  const int* __restrict__ bias,
                  float* __restrict__ O,
                  int N, int K, int nbn,
                  const float* __restrict__ pAin,
                  const float* __restrict__ pAw) {
  __shared__ signed char slds[65536];
  signed char* ldsA = slds;            // bufs at 0 / 16K
  signed char* ldsB = slds + 32768;    // bufs at 0 / 16K

  const int nwg = gridDim.x, bid = blockIdx.x, per = nwg >> 3;
  const int swz = (bid & 7) * per + (bid >> 3);
  const int brow = swz / nbn, bcol = swz - brow * nbn;
  const int browBase = brow << 7, bcolBase = bcol << 7;

  const int tid = threadIdx.x;
  const int lane = tid & 63, l15 = lane & 15, hi = lane >> 4;
  const int wid = tid >> 6;
  const int wr = (wid >> 1) << 6, wc = (wid & 1) << 6;

  v4i acc[4][4] = {};
  v4i aK0[4], aK1[4], bK[4];

  const int nk = K >> 7, niter = nk >> 1, nkm = nk - 1;

  STG128(0, 0);
  VMC0();
  BARRIER();
  LDA4_128(0, 0, aK0);

#pragma unroll 1
  for (int i = 0; i < niter; ++i) {
    const int tO = 2 * i + 1;
    const int tE = (2 * i + 2) & nkm;
    // tile 2i (buf0)
    LGK(4);
    BARRIER();
    STG128(1, tO);
    LDB4_128(0, 0); FENCE(); LDA4_128(0, 1, aK1);
    LGK(4);
    MFMA16(aK0);
    VMC0();
    BARRIER();
    LDB4_128(0, 1); FENCE(); LDA4_128(1, 0, aK0);
    LGK(4);
    MFMA16(aK1);
    // tile 2i+1 (buf1)
    LGK(4);
    BARRIER();
    STG128(0, tE);
    LDB4_128(1, 0); FENCE(); LDA4_128(1, 1, aK1);
    LGK(4);
    MFMA16(aK0);
    VMC0();
    BARRIER();
    LDB4_128(1, 1); FENCE(); LDA4_128(0, 0, aK0);
    LGK(4);
    MFMA16(aK1);
  }

  VMC0();

  const float sDeq = (pAw[0] * pAin[0]) / (QMAX * QMAX);
#pragma unroll
  for (int n = 0; n < 4; ++n) {
    int gcol = bcolBase + wc + n * 16 + l15;
    int bv = bias[gcol];
#pragma unroll
    for (int m = 0; m < 4; ++m) {
      int growb = browBase + wr + m * 16 + (hi << 2);
#pragma unroll
      for (int r = 0; r < 4; ++r) {
        O[(size_t)(growb + r) * N + gcol] = (float)(acc[m][n][r] + bv) * sDeq;
      }
    }
  }
}

extern "C" void kernel_launch(void* const* d_in, const int* in_sizes, int n_in,
                              void* d_out, int out_size, void* d_ws, size_t ws_size,
                              hipStream_t stream) {
  const float* x     = (const float*)d_in[0];
  const float* a_in0 = (const float*)d_in[1];
  const float* a_w0  = (const float*)d_in[2];
  const float* a_in2 = (const float*)d_in[3];
  const float* a_w2  = (const float*)d_in[4];
  const float* a_in4 = (const float*)d_in[5];
  const float* a_w4  = (const float*)d_in[6];
  const int*   W0    = (const int*)d_in[7];
  const int*   W1    = (const int*)d_in[8];
  const int*   W2    = (const int*)d_in[9];
  float* out = (float*)d_out;

  constexpr int B = 4096, IN = 1024, H0 = 4096, H1 = 4096, OUTN = 1024;

  char* ws = (char*)d_ws;
  size_t off = 0;
  auto alloc = [&](size_t sz) {
    char* p = ws + off;
    off += (sz + 255) & ~(size_t)255;
    return p;
  };
  signed char* qa0 = (signed char*)alloc((size_t)B * IN);
  signed char* qa1 = (signed char*)alloc((size_t)B * H0);
  signed char* qa2 = (signed char*)alloc((size_t)B * H1);
  signed char* W0p = (signed char*)alloc((size_t)H0 * IN);
  signed char* W1p = (signed char*)alloc((size_t)H1 * H0);
  signed char* W2p = (signed char*)alloc((size_t)OUTN * H1);
  int* b0 = (int*)alloc((size_t)H0 * 4);
  int* b1 = (int*)alloc((size_t)H1 * 4);
  int* b2 = (int*)alloc((size_t)OUTN * 4);

  hipFuncSetAttribute((const void*)qgemm256_kernel,
                      hipFuncAttributeMaxDynamicSharedMemorySize, 131072);

  // merged prep: pack W0/W1/W2 + quantize x (1 launch, 28672 blocks)
  prep_kernel<<<28672, 256, 0, stream>>>(x, qa0, a_in0,
                                         W0, W0p, b0,
                                         W1, W1p, b1,
                                         W2, W2p, b2);

  // layer 0: [B,IN]x[H0,IN]^T -> qa1 (int8), 8-phase 256^2, grid 16x16=256
  qgemm256_kernel<<<(B / 256) * (H0 / 256), 512, 131072, stream>>>(
      qa0, W0p, b0, qa1, H0, IN, H0 / 256, a_in0, a_w0, a_in2);

  // layer 1: [B,H0]x[H1,H0]^T -> qa2 (int8), 8-phase 256^2, grid 16x16=256
  qgemm256_kernel<<<(B / 256) * (H1 / 256), 512, 131072, stream>>>(
      qa1, W1p, b1, qa2, H1, H0, H1 / 256, a_in2, a_w2, a_in4);

  // layer 2: [B,H1]x[OUT,H1]^T -> f32 out, 128^2 k-split, grid 32x8=256
  qgemm_kernel<<<(B / 128) * (OUTN / 128), 256, 0, stream>>>(
      qa2, W2p, b2, out, OUTN, H1, OUTN / 128, a_in4, a_w4);
}